// Round 12
// baseline (269.107 us; speedup 1.0000x reference)
//
#include <hip/hip_runtime.h>
#include <cstdint>
#include <cmath>

typedef unsigned short u16;
typedef __bf16 bf16_t;
typedef bf16_t bf16x8 __attribute__((ext_vector_type(8)));
typedef float f32x4 __attribute__((ext_vector_type(4)));
typedef u16 u16x8 __attribute__((ext_vector_type(8)));
typedef u16 u16x4 __attribute__((ext_vector_type(4)));

#define DEV __device__ __forceinline__

DEV u16 f2b(float f) {
    uint32_t u = __builtin_bit_cast(uint32_t, f);
    u += 0x7FFFu + ((u >> 16) & 1u);
    return (u16)(u >> 16);
}
DEV float b2f(u16 h) { return __builtin_bit_cast(float, (uint32_t)h << 16); }

DEV bf16x8 load8(const u16* p) {
    return __builtin_bit_cast(bf16x8, *reinterpret_cast<const u16x8*>(p));
}

DEV void async16(void* lds, const void* g) {
    __builtin_amdgcn_global_load_lds(
        reinterpret_cast<const __attribute__((address_space(1))) void*>(
            reinterpret_cast<uintptr_t>(g)),
        reinterpret_cast<__attribute__((address_space(3))) void*>(
            reinterpret_cast<uintptr_t>(lds)),
        16, 0, 0);
}

DEV float gelu_t(float x) {
    float z = 0.7978845608028654f * (x + 0.044715f * x * x * x);
    z = fminf(fmaxf(z, -15.0f), 15.0f);
    float e = __expf(2.0f * z);
    return 0.5f * x * (1.0f + (e - 1.0f) / (e + 1.0f));
}

// ---------------- LayerNorm fp32-in: 1 wave per row of 768 -> bf16 ----------------
__global__ __launch_bounds__(256) void ln_k(const float* __restrict__ x,
                                            const float* __restrict__ g,
                                            const float* __restrict__ bb,
                                            u16* __restrict__ out) {
    const int lane = threadIdx.x & 63, w = threadIdx.x >> 6;
    const int row = blockIdx.x * 4 + w;
    const float4* xr = reinterpret_cast<const float4*>(x + (size_t)row * 768);
    float4 v[3];
    float s = 0.f, s2 = 0.f;
#pragma unroll
    for (int i = 0; i < 3; ++i) {
        v[i] = xr[i * 64 + lane];
        s += v[i].x + v[i].y + v[i].z + v[i].w;
        s2 += v[i].x * v[i].x + v[i].y * v[i].y + v[i].z * v[i].z + v[i].w * v[i].w;
    }
#pragma unroll
    for (int off = 1; off < 64; off <<= 1) {
        s += __shfl_xor(s, off);
        s2 += __shfl_xor(s2, off);
    }
    const float mu = s * (1.0f / 768.0f);
    const float rstd = rsqrtf(s2 * (1.0f / 768.0f) - mu * mu + 1e-5f);
#pragma unroll
    for (int i = 0; i < 3; ++i) {
        int col = i * 256 + lane * 4;
        u16x4 o;
        o[0] = f2b((v[i].x - mu) * rstd * g[col + 0] + bb[col + 0]);
        o[1] = f2b((v[i].y - mu) * rstd * g[col + 1] + bb[col + 1]);
        o[2] = f2b((v[i].z - mu) * rstd * g[col + 2] + bb[col + 2]);
        o[3] = f2b((v[i].w - mu) * rstd * g[col + 3] + bb[col + 3]);
        *reinterpret_cast<u16x4*>(out + (size_t)row * 768 + col) = o;
    }
}

// ---------------- LayerNorm bf16-in: 1 wave per row of 768 -> bf16 ----------------
__global__ __launch_bounds__(256) void ln_b16(const u16* __restrict__ x,
                                              const float* __restrict__ g,
                                              const float* __restrict__ bb,
                                              u16* __restrict__ out) {
    const int lane = threadIdx.x & 63, w = threadIdx.x >> 6;
    const int row = blockIdx.x * 4 + w;
    const u16* xr = x + (size_t)row * 768;
    float v[12];
    float s = 0.f, s2 = 0.f;
#pragma unroll
    for (int i = 0; i < 3; ++i) {
        u16x4 u = *reinterpret_cast<const u16x4*>(xr + i * 256 + lane * 4);
#pragma unroll
        for (int jj = 0; jj < 4; ++jj) {
            float f = b2f(u[jj]);
            v[i * 4 + jj] = f;
            s += f;
            s2 += f * f;
        }
    }
#pragma unroll
    for (int off = 1; off < 64; off <<= 1) {
        s += __shfl_xor(s, off);
        s2 += __shfl_xor(s2, off);
    }
    const float mu = s * (1.0f / 768.0f);
    const float rstd = rsqrtf(s2 * (1.0f / 768.0f) - mu * mu + 1e-5f);
#pragma unroll
    for (int i = 0; i < 3; ++i) {
        int col = i * 256 + lane * 4;
        u16x4 o;
#pragma unroll
        for (int jj = 0; jj < 4; ++jj)
            o[jj] = f2b((v[i * 4 + jj] - mu) * rstd * g[col + jj] + bb[col + jj]);
        *reinterpret_cast<u16x4*>(out + (size_t)row * 768 + col) = o;
    }
}

// ------------- weight fp32 [K][N] -> bf16 transposed [N][K] (32x32 tiles) -------------
__global__ __launch_bounds__(256) void wconv_k(const float* __restrict__ W,
                                               u16* __restrict__ WT, int K, int N) {
    __shared__ float tile[32][33];
    const int tx = threadIdx.x, ty = threadIdx.y;
    const int n0 = blockIdx.x * 32, k0 = blockIdx.y * 32;
#pragma unroll
    for (int i = 0; i < 4; ++i)
        tile[ty + i * 8][tx] = W[(size_t)(k0 + ty + i * 8) * N + n0 + tx];
    __syncthreads();
#pragma unroll
    for (int i = 0; i < 4; ++i)
        WT[(size_t)(n0 + ty + i * 8) * K + k0 + tx] = f2b(tile[tx][ty + i * 8]);
}

// ------------- v (from qkv [8192][2304]) -> vT [96*64][1024] bf16 -------------
__global__ __launch_bounds__(256) void vtrans_k(const u16* __restrict__ qkv,
                                                u16* __restrict__ vT) {
    __shared__ u16 tile[32][33];
    const int tx = threadIdx.x, ty = threadIdx.y;
    const int t0 = blockIdx.x * 32, d0 = blockIdx.y * 32, bh = blockIdx.z;
    const int b = bh / 12, hd = bh % 12;
#pragma unroll
    for (int i = 0; i < 4; ++i)
        tile[ty + i * 8][tx] =
            qkv[(size_t)(b * 1024 + t0 + ty + i * 8) * 2304 + 1536 + hd * 64 + d0 + tx];
    __syncthreads();
#pragma unroll
    for (int i = 0; i < 4; ++i)
        vT[(size_t)(bh * 64 + d0 + ty + i * 8) * 1024 + t0 + tx] = tile[tx][ty + i * 8];
}

// ------------- GEMM 128x128, BK=32, 4 waves, 3-slot rotation -------------------------
// For small-grid shapes (proj, fc2). Both-sides XOR swizzle, M-major XCD swizzle.
// RESIDT: 0 none, 1 fp32, 2 bf16.
template <int ACT, int RESIDT, int OUTBF>
__global__ __launch_bounds__(256) void gemm_bt(const u16* __restrict__ A,
                                               const u16* __restrict__ BT,
                                               const float* __restrict__ bias,
                                               const void* __restrict__ resid,
                                               void* __restrict__ out,
                                               int M, int N, int K) {
    __shared__ u16 As[3][128 * 32];
    __shared__ u16 Bs[3][128 * 32];
    const int tid = threadIdx.x, lane = tid & 63;
    const int l15 = lane & 15, lg = lane >> 4;
    const int nx = gridDim.x;
    const int bid = blockIdx.y * nx + blockIdx.x;
    const int q = (nx * gridDim.y) >> 3;
    const int swz = (bid & 7) * q + (bid >> 3);
    const int mBase = (swz / nx) * 128, nBase = (swz % nx) * 128;
    const int w = tid >> 6, wr = w >> 1, wc = w & 1;

    auto stage = [&](int buf, int kk) {
        const int k0 = kk << 5;
#pragma unroll
        for (int i = 0; i < 2; ++i) {
            int c = i * 256 + tid;
            int row = c >> 2;
            int g = ((c & 3) ^ ((row >> 1) & 3)) << 3;
            async16(As[buf] + c * 8, A + (size_t)(mBase + row) * K + k0 + g);
        }
#pragma unroll
        for (int i = 0; i < 2; ++i) {
            int c = i * 256 + tid;
            int row = c >> 2;
            int g = ((c & 3) ^ ((row >> 1) & 3)) << 3;
            async16(Bs[buf] + c * 8, BT + (size_t)(nBase + row) * K + k0 + g);
        }
    };

    f32x4 acc[4][4] = {};
    const int nsteps = K >> 5;
    stage(0, 0);
    stage(1, 1);
    int cur = 0;
    for (int kk = 0; kk < nsteps; ++kk) {
        if (kk + 2 < nsteps) {
            int nb = cur + 2;
            if (nb >= 3) nb -= 3;
            stage(nb, kk + 2);
            asm volatile("s_waitcnt vmcnt(8)" ::: "memory");
        } else if (kk + 1 < nsteps) {
            asm volatile("s_waitcnt vmcnt(4)" ::: "memory");
        } else {
            asm volatile("s_waitcnt vmcnt(0)" ::: "memory");
        }
        __builtin_amdgcn_s_barrier();
        asm volatile("" ::: "memory");

        bf16x8 af[4], bfr[4];
#pragma unroll
        for (int mi = 0; mi < 4; ++mi) {
            int rA = wr * 64 + mi * 16 + l15;
            af[mi] = load8(As[cur] + rA * 32 + ((lg ^ ((rA >> 1) & 3)) << 3));
        }
#pragma unroll
        for (int ni = 0; ni < 4; ++ni) {
            int rB = wc * 64 + ni * 16 + l15;
            bfr[ni] = load8(Bs[cur] + rB * 32 + ((lg ^ ((rB >> 1) & 3)) << 3));
        }
        __builtin_amdgcn_s_setprio(1);
#pragma unroll
        for (int mi = 0; mi < 4; ++mi)
#pragma unroll
            for (int ni = 0; ni < 4; ++ni)
                acc[mi][ni] = __builtin_amdgcn_mfma_f32_16x16x32_bf16(
                    af[mi], bfr[ni], acc[mi][ni], 0, 0, 0);
        __builtin_amdgcn_s_setprio(0);

        asm volatile("" ::: "memory");
        __builtin_amdgcn_s_barrier();
        asm volatile("" ::: "memory");
        cur = (cur == 2) ? 0 : cur + 1;
    }
#pragma unroll
    for (int mi = 0; mi < 4; ++mi) {
#pragma unroll
        for (int ni = 0; ni < 4; ++ni) {
            const int row0 = mBase + wr * 64 + mi * 16 + lg * 4;
            const int col = nBase + wc * 64 + ni * 16 + l15;
            const float bv = bias[col];
#pragma unroll
            for (int r = 0; r < 4; ++r) {
                float v = acc[mi][ni][r] + bv;
                if (ACT == 1) v = gelu_t(v);
                size_t off = (size_t)(row0 + r) * N + col;
                if (RESIDT == 1) v += ((const float*)resid)[off];
                if (RESIDT == 2) v += b2f(((const u16*)resid)[off]);
                if (OUTBF)
                    ((u16*)out)[off] = f2b(v);
                else
                    ((float*)out)[off] = v;
            }
        }
    }
}

// ------------- GEMM 256x256, 8 waves (2Mx4N), BK=32, 4-slot rotation -----------------
// For machine-filling grids (qkv, fc1). ONE barrier per K-step (4 slots + stage(t+2)
// make the second barrier unnecessary); stages interleaved inside the 2 MFMA phases.
// r6-measured ~1000 TF on fc1. RESIDT: 0 none, 1 fp32, 2 bf16.
template <int ACT, int RESIDT, int OUTBF>
__global__ __launch_bounds__(512, 2) void gemm256(const u16* __restrict__ A,
                                                  const u16* __restrict__ BT,
                                                  const float* __restrict__ bias,
                                                  const void* __restrict__ resid,
                                                  void* __restrict__ out,
                                                  int M, int N, int K) {
    __shared__ u16 As[4][256 * 32];  // 64 KB
    __shared__ u16 Bs[4][256 * 32];  // 64 KB
    const int tid = threadIdx.x, lane = tid & 63;
    const int l15 = lane & 15, lg = lane >> 4;
    const int w = tid >> 6, wr = w >> 2, wc = w & 3;  // 2 x 4 waves
    const int gx = gridDim.x;
    const int bid = blockIdx.y * gx + blockIdx.x;
    const int q = (gx * gridDim.y) >> 3;
    const int swz = (bid & 7) * q + (bid >> 3);
    const int mBase = (swz / gx) * 256, nBase = (swz % gx) * 256;

    auto stageA = [&](int slot, int t) {
#pragma unroll
        for (int i = 0; i < 2; ++i) {
            int c = i * 512 + tid;                  // 0..1023 chunks of 16 B
            int row = c >> 2;                       // 256 rows x 4 chunks
            int g = (c & 3) ^ ((row >> 1) & 3);     // inverse swizzle on source
            async16(As[slot] + c * 8, A + (size_t)(mBase + row) * K + t * 32 + g * 8);
        }
    };
    auto stageB = [&](int slot, int t) {
#pragma unroll
        for (int i = 0; i < 2; ++i) {
            int c = i * 512 + tid;
            int row = c >> 2;
            int g = (c & 3) ^ ((row >> 1) & 3);
            async16(Bs[slot] + c * 8, BT + (size_t)(nBase + row) * K + t * 32 + g * 8);
        }
    };

    f32x4 acc[8][4] = {};
    const int swzr = (l15 >> 1) & 3;  // read-side swizzle
    const int nk = K >> 5;

    stageA(0, 0);
    stageB(0, 0);
    stageA(1, 1);
    stageB(1, 1);

    for (int t = 0; t < nk; ++t) {
        const int slot = t & 3;
        if (t + 1 < nk) {
            asm volatile("s_waitcnt vmcnt(4)" ::: "memory");
        } else {
            asm volatile("s_waitcnt vmcnt(0)" ::: "memory");
        }
        __builtin_amdgcn_s_barrier();
        asm volatile("" ::: "memory");

        const u16* Ab = As[slot];
        const u16* Bb = Bs[slot];
        // ---- phase 1: B frags + A quadrant 0 (mi 0..3) ----
        if (t + 2 < nk) stageA((t + 2) & 3, t + 2);
        bf16x8 bf[4], af[4];
#pragma unroll
        for (int ni = 0; ni < 4; ++ni)
            bf[ni] = load8(Bb + (wc * 64 + ni * 16 + l15) * 32 + ((lg ^ swzr) << 3));
#pragma unroll
        for (int mi = 0; mi < 4; ++mi)
            af[mi] = load8(Ab + (wr * 128 + mi * 16 + l15) * 32 + ((lg ^ swzr) << 3));
        asm volatile("s_waitcnt lgkmcnt(0)" ::: "memory");
        __builtin_amdgcn_sched_barrier(0);
        __builtin_amdgcn_s_setprio(1);
#pragma unroll
        for (int mi = 0; mi < 4; ++mi)
#pragma unroll
            for (int ni = 0; ni < 4; ++ni)
                acc[mi][ni] = __builtin_amdgcn_mfma_f32_16x16x32_bf16(
                    af[mi], bf[ni], acc[mi][ni], 0, 0, 0);
        __builtin_amdgcn_s_setprio(0);
        // ---- phase 2: A quadrant 1 (mi 4..7) ----
        if (t + 2 < nk) stageB((t + 2) & 3, t + 2);
        bf16x8 af2[4];
#pragma unroll
        for (int mi = 0; mi < 4; ++mi)
            af2[mi] =
                load8(Ab + (wr * 128 + 64 + mi * 16 + l15) * 32 + ((lg ^ swzr) << 3));
        asm volatile("s_waitcnt lgkmcnt(0)" ::: "memory");
        __builtin_amdgcn_sched_barrier(0);
        __builtin_amdgcn_s_setprio(1);
#pragma unroll
        for (int mi = 0; mi < 4; ++mi)
#pragma unroll
            for (int ni = 0; ni < 4; ++ni)
                acc[mi + 4][ni] = __builtin_amdgcn_mfma_f32_16x16x32_bf16(
                    af2[mi], bf[ni], acc[mi + 4][ni], 0, 0, 0);
        __builtin_amdgcn_s_setprio(0);
        asm volatile("" ::: "memory");
    }

    // ---- epilogue ----
#pragma unroll
    for (int mi = 0; mi < 8; ++mi) {
#pragma unroll
        for (int ni = 0; ni < 4; ++ni) {
            const int row0 = mBase + wr * 128 + mi * 16 + lg * 4;
            const int col = nBase + wc * 64 + ni * 16 + l15;
            const float bv = bias[col];
#pragma unroll
            for (int r = 0; r < 4; ++r) {
                float v = acc[mi][ni][r] + bv;
                if (ACT == 1) v = gelu_t(v);
                size_t off = (size_t)(row0 + r) * N + col;
                if (RESIDT == 1) v += ((const float*)resid)[off];
                if (RESIDT == 2) v += b2f(((const u16*)resid)[off]);
                if (OUTBF)
                    ((u16*)out)[off] = f2b(v);
                else
                    ((float*)out)[off] = v;
            }
        }
    }
}

// ------------- causal flash attention: swapped QK^T + in-register softmax -------------
__global__ __launch_bounds__(256, 3) void attn_k(const u16* __restrict__ qkv,
                                                 const u16* __restrict__ vT,
                                                 u16* __restrict__ y) {
    __shared__ u16 Ks[2][64 * 64];
    __shared__ u16 Vs[2][64 * 64];
    __shared__ u16 Ps[4][2][16 * 64];
    const int tid = threadIdx.x, lane = tid & 63, w = tid >> 6;
    const int bid = blockIdx.x;
    const uint32_t permPk = 2u | (7u << 3) | (1u << 6) | (4u << 9) | (6u << 12) |
                            (0u << 15) | (5u << 18) | (3u << 21);
    const int qt = (permPk >> (((bid + (bid >> 8)) & 7) * 3)) & 7;
    const int bh = ((bid >> 8) << 5) + ((bid & 255) >> 3);
    const int b = bh / 12, hd = bh % 12;
    const int l15 = lane & 15, lg = lane >> 4;
    const int r0 = qt * 128 + w * 32;

    const float qscale = 0.125f * 1.4426950408889634f;
    bf16x8 qf[2][2];
#pragma unroll
    for (int m = 0; m < 2; ++m) {
        const u16* qb = qkv + (size_t)(b * 1024 + r0 + m * 16 + l15) * 2304 + hd * 64;
#pragma unroll
        for (int ks = 0; ks < 2; ++ks) {
            u16x8 u = *reinterpret_cast<const u16x8*>(qb + ks * 32 + lg * 8);
            u16x8 o;
#pragma unroll
            for (int jj = 0; jj < 8; ++jj) o[jj] = f2b(b2f(u[jj]) * qscale);
            qf[m][ks] = __builtin_bit_cast(bf16x8, o);
        }
    }

    const u16* kbase = qkv + (size_t)(b * 1024) * 2304 + 768 + hd * 64;
    const u16* vbase = vT + (size_t)(bh * 64) * 1024;

    auto stage = [&](int buf, int j) {
#pragma unroll
        for (int i = 0; i < 2; ++i) {
            int c = i * 256 + tid;
            int row = c >> 3, sc = ((c & 7) ^ (row & 7)) << 3;
            async16(Ks[buf] + c * 8, kbase + (size_t)(j * 64 + row) * 2304 + sc);
        }
#pragma unroll
        for (int i = 0; i < 2; ++i) {
            int c = i * 256 + tid;
            int row = c >> 3, sc = ((c & 7) ^ (row & 7)) << 3;
            async16(Vs[buf] + c * 8, vbase + (size_t)row * 1024 + j * 64 + sc);
        }
    };

    f32x4 oacc[2][4] = {};
    float mrow[2] = {-1e30f, -1e30f};
    float lrow[2] = {0.f, 0.f};

    const int jd = (r0 + 31) >> 6;
    const int jmax = qt * 2 + 1;

    stage(0, 0);
    for (int j = 0; j <= jmax; ++j) {
        const int cur = j & 1;
        if (j < jmax) {
            stage(cur ^ 1, j + 1);
            asm volatile("s_waitcnt vmcnt(4)" ::: "memory");
        } else {
            asm volatile("s_waitcnt vmcnt(0)" ::: "memory");
        }
        __builtin_amdgcn_s_barrier();
        asm volatile("" ::: "memory");

        if (j <= jd) {
            const bool diag = (j == jd);
            const u16* Kc = Ks[cur];
            const u16* Vc = Vs[cur];
            f32x4 s[2][4] = {};
            __builtin_amdgcn_s_setprio(1);
#pragma unroll
            for (int ks = 0; ks < 2; ++ks) {
                bf16x8 kf[4];
#pragma unroll
                for (int ni = 0; ni < 4; ++ni) {
                    int key = ni * 16 + l15;
                    kf[ni] = load8(Kc + key * 64 + (((ks * 4 + lg) ^ (key & 7)) << 3));
                }
#pragma unroll
                for (int ni = 0; ni < 4; ++ni) {
                    s[0][ni] = __builtin_amdgcn_mfma_f32_16x16x32_bf16(
                        kf[ni], qf[0][ks], s[0][ni], 0, 0, 0);
                    s[1][ni] = __builtin_amdgcn_mfma_f32_16x16x32_bf16(
                        kf[ni], qf[1][ks], s[1][ni], 0, 0, 0);
                }
            }
            __builtin_amdgcn_s_setprio(0);

#pragma unroll
            for (int m = 0; m < 2; ++m) {
                if (diag) {
                    const int qrow = r0 + m * 16 + l15;
#pragma unroll
                    for (int ni = 0; ni < 4; ++ni) {
                        int key = j * 64 + ni * 16 + lg * 4;
#pragma unroll
                        for (int r = 0; r < 4; ++r)
                            if (key + r > qrow) s[m][ni][r] = -1e30f;
                    }
                }
                float pmax = -1e30f;
#pragma unroll
                for (int ni = 0; ni < 4; ++ni)
#pragma unroll
                    for (int r = 0; r < 4; ++r) pmax = fmaxf(pmax, s[m][ni][r]);
                pmax = fmaxf(pmax, __shfl_xor(pmax, 16));
                pmax = fmaxf(pmax, __shfl_xor(pmax, 32));

                if (!__all(pmax <= mrow[m] + 8.0f)) {
                    float mnew = fmaxf(mrow[m], pmax);
                    float scal = exp2f(mrow[m] - mnew);
                    mrow[m] = mnew;
                    lrow[m] *= scal;
#pragma unroll
                    for (int r = 0; r < 4; ++r) {
                        float sr = __shfl(scal, lg * 4 + r);
#pragma unroll
                        for (int ni = 0; ni < 4; ++ni) oacc[m][ni][r] *= sr;
                    }
                }
                float psum = 0.f;
#pragma unroll
                for (int ni = 0; ni < 4; ++ni) {
                    u16x4 pk;
#pragma unroll
                    for (int r = 0; r < 4; ++r) {
                        float pv = exp2f(s[m][ni][r] - mrow[m]);
                        psum += pv;
                        pk[r] = f2b(pv);
                    }
                    *reinterpret_cast<u16x4*>(
                        &Ps[w][m][l15 * 64 + ((ni * 16 + lg * 4) ^ ((l15 & 7) << 3))]) =
                        pk;
                }
                psum += __shfl_xor(psum, 16);
                psum += __shfl_xor(psum, 32);
                lrow[m] += psum;
            }

            __builtin_amdgcn_s_setprio(1);
#pragma unroll
            for (int ks = 0; ks < 2; ++ks) {
                bf16x8 pf0 = load8(
                    &Ps[w][0][l15 * 64 + ((ks * 32 + lg * 8) ^ ((l15 & 7) << 3))]);
                bf16x8 pf1 = load8(
                    &Ps[w][1][l15 * 64 + ((ks * 32 + lg * 8) ^ ((l15 & 7) << 3))]);
                bf16x8 vf[4];
#pragma unroll
                for (int ni = 0; ni < 4; ++ni) {
                    int d = ni * 16 + l15;
                    vf[ni] = load8(Vc + d * 64 + (((ks * 4 + lg) ^ (d & 7)) << 3));
                }
#pragma unroll
                for (int ni = 0; ni < 4; ++ni) {
                    oacc[0][ni] = __builtin_amdgcn_mfma_f32_16x16x32_bf16(
                        pf0, vf[ni], oacc[0][ni], 0, 0, 0);
                    oacc[1][ni] = __builtin_amdgcn_mfma_f32_16x16x32_bf16(
                        pf1, vf[ni], oacc[1][ni], 0, 0, 0);
                }
            }
            __builtin_amdgcn_s_setprio(0);
        }
        asm volatile("" ::: "memory");
        __builtin_amdgcn_s_barrier();
        asm volatile("" ::: "memory");
    }

#pragma unroll
    for (int m = 0; m < 2; ++m) {
#pragma unroll
        for (int r = 0; r < 4; ++r) {
            float rl = 1.0f / __shfl(lrow[m], lg * 4 + r);
            int row = r0 + m * 16 + lg * 4 + r;
#pragma unroll
            for (int ni = 0; ni < 4; ++ni) {
                int col = hd * 64 + ni * 16 + l15;
                y[(size_t)(b * 1024 + row) * 768 + col] = f2b(oacc[m][ni][r] * rl);
            }
        }
    }
}

extern "C" void kernel_launch(void* const* d_in, const int* in_sizes, int n_in,
                              void* d_out, int out_size, void* d_ws, size_t ws_size,
                              hipStream_t stream) {
    const float* x      = (const float*)d_in[0];
    const float* ln1_g  = (const float*)d_in[1];
    const float* ln1_b  = (const float*)d_in[2];
    const float* w_attn = (const float*)d_in[3];
    const float* b_attn = (const float*)d_in[4];
    const float* w_proj = (const float*)d_in[5];
    const float* b_proj = (const float*)d_in[6];
    const float* ln2_g  = (const float*)d_in[7];
    const float* ln2_b  = (const float*)d_in[8];
    const float* w_fc1  = (const float*)d_in[9];
    const float* b_fc1  = (const float*)d_in[10];
    const float* w_fc2  = (const float*)d_in[11];
    const float* b_fc2  = (const float*)d_in[12];
    float* out = (float*)d_out;

    char* p = (char*)d_ws;
    auto take = [&](size_t n) {
        char* r = p;
        p += (n + 255) & ~(size_t)255;
        return r;
    };
    u16* wT_attn = (u16*)take((size_t)2304 * 768 * 2);
    u16* wT_proj = (u16*)take((size_t)768 * 768 * 2);
    u16* wT_fc1  = (u16*)take((size_t)3072 * 768 * 2);
    u16* wT_fc2  = (u16*)take((size_t)768 * 3072 * 2);
    u16* h       = (u16*)take((size_t)8192 * 768 * 2);   // h1 / h2 (aliased)
    u16* bufA    = (u16*)take((size_t)50331648);         // qkv+vT, later g1
    u16* yb      = (u16*)take((size_t)8192 * 768 * 2);
    u16* x1b     = (u16*)take((size_t)8192 * 768 * 2);   // residual stream, bf16
    u16* qkv = bufA;
    u16* vT  = bufA + (size_t)8192 * 2304;
    u16* g1  = bufA;

    const dim3 tb(32, 8);
    // weight convert+transpose
    wconv_k<<<dim3(2304 / 32, 768 / 32), tb, 0, stream>>>(w_attn, wT_attn, 768, 2304);
    wconv_k<<<dim3(768 / 32, 768 / 32), tb, 0, stream>>>(w_proj, wT_proj, 768, 768);
    wconv_k<<<dim3(3072 / 32, 768 / 32), tb, 0, stream>>>(w_fc1, wT_fc1, 768, 3072);
    wconv_k<<<dim3(768 / 32, 3072 / 32), tb, 0, stream>>>(w_fc2, wT_fc2, 3072, 768);
    // ln1
    ln_k<<<2048, 256, 0, stream>>>(x, ln1_g, ln1_b, h);
    // qkv = h @ w_attn + b_attn  -> bf16   (256^2, machine-filling grid)
    gemm256<0, 0, 1><<<dim3(9, 32), 512, 0, stream>>>(h, wT_attn, b_attn, nullptr,
                                                      qkv, 8192, 2304, 768);
    // v transpose
    vtrans_k<<<dim3(32, 2, 96), tb, 0, stream>>>(qkv, vT);
    // attention
    attn_k<<<768, 256, 0, stream>>>(qkv, vT, yb);
    // x1b = bf16(x + y @ w_proj + b_proj)   (128^2, 384 blocks)
    gemm_bt<0, 1, 1><<<dim3(6, 64), 256, 0, stream>>>(yb, wT_proj, b_proj, x,
                                                      x1b, 8192, 768, 768);
    // ln2 (bf16 input)
    ln_b16<<<2048, 256, 0, stream>>>(x1b, ln2_g, ln2_b, h);
    // g1 = gelu(h @ w_fc1 + b_fc1) -> bf16  (256^2, machine-filling grid)
    gemm256<1, 0, 1><<<dim3(12, 32), 512, 0, stream>>>(h, wT_fc1, b_fc1, nullptr,
                                                       g1, 8192, 3072, 768);
    // out = x1b + g1 @ w_fc2 + b_fc2  (fp32 out, bf16 resid; 128^2, 384 blocks)
    gemm_bt<0, 2, 0><<<dim3(6, 64), 256, 0, stream>>>(g1, wT_fc2, b_fc2, x1b,
                                                      out, 8192, 768, 3072);
}

// Round 13
// 245.263 us; speedup vs baseline: 1.0972x; 1.0972x over previous
//
#include <hip/hip_runtime.h>
#include <cstdint>
#include <cmath>

typedef unsigned short u16;
typedef __bf16 bf16_t;
typedef bf16_t bf16x8 __attribute__((ext_vector_type(8)));
typedef float f32x4 __attribute__((ext_vector_type(4)));
typedef u16 u16x8 __attribute__((ext_vector_type(8)));
typedef u16 u16x4 __attribute__((ext_vector_type(4)));

#define DEV __device__ __forceinline__

DEV u16 f2b(float f) {
    uint32_t u = __builtin_bit_cast(uint32_t, f);
    u += 0x7FFFu + ((u >> 16) & 1u);
    return (u16)(u >> 16);
}
DEV float b2f(u16 h) { return __builtin_bit_cast(float, (uint32_t)h << 16); }

DEV bf16x8 load8(const u16* p) {
    return __builtin_bit_cast(bf16x8, *reinterpret_cast<const u16x8*>(p));
}

DEV void async16(void* lds, const void* g) {
    __builtin_amdgcn_global_load_lds(
        reinterpret_cast<const __attribute__((address_space(1))) void*>(
            reinterpret_cast<uintptr_t>(g)),
        reinterpret_cast<__attribute__((address_space(3))) void*>(
            reinterpret_cast<uintptr_t>(lds)),
        16, 0, 0);
}

DEV float gelu_t(float x) {
    float z = 0.7978845608028654f * (x + 0.044715f * x * x * x);
    z = fminf(fmaxf(z, -15.0f), 15.0f);
    float e = __expf(2.0f * z);
    return 0.5f * x * (1.0f + (e - 1.0f) / (e + 1.0f));
}

// ---------------- LayerNorm fp32-in: 1 wave per row of 768 -> bf16 ----------------
__global__ __launch_bounds__(256) void ln_k(const float* __restrict__ x,
                                            const float* __restrict__ g,
                                            const float* __restrict__ bb,
                                            u16* __restrict__ out) {
    const int lane = threadIdx.x & 63, w = threadIdx.x >> 6;
    const int row = blockIdx.x * 4 + w;
    const float4* xr = reinterpret_cast<const float4*>(x + (size_t)row * 768);
    float4 v[3];
    float s = 0.f, s2 = 0.f;
#pragma unroll
    for (int i = 0; i < 3; ++i) {
        v[i] = xr[i * 64 + lane];
        s += v[i].x + v[i].y + v[i].z + v[i].w;
        s2 += v[i].x * v[i].x + v[i].y * v[i].y + v[i].z * v[i].z + v[i].w * v[i].w;
    }
#pragma unroll
    for (int off = 1; off < 64; off <<= 1) {
        s += __shfl_xor(s, off);
        s2 += __shfl_xor(s2, off);
    }
    const float mu = s * (1.0f / 768.0f);
    const float rstd = rsqrtf(s2 * (1.0f / 768.0f) - mu * mu + 1e-5f);
#pragma unroll
    for (int i = 0; i < 3; ++i) {
        int col = i * 256 + lane * 4;
        u16x4 o;
        o[0] = f2b((v[i].x - mu) * rstd * g[col + 0] + bb[col + 0]);
        o[1] = f2b((v[i].y - mu) * rstd * g[col + 1] + bb[col + 1]);
        o[2] = f2b((v[i].z - mu) * rstd * g[col + 2] + bb[col + 2]);
        o[3] = f2b((v[i].w - mu) * rstd * g[col + 3] + bb[col + 3]);
        *reinterpret_cast<u16x4*>(out + (size_t)row * 768 + col) = o;
    }
}

// ---------------- LayerNorm bf16-in: 1 wave per row of 768 -> bf16 ----------------
__global__ __launch_bounds__(256) void ln_b16(const u16* __restrict__ x,
                                              const float* __restrict__ g,
                                              const float* __restrict__ bb,
                                              u16* __restrict__ out) {
    const int lane = threadIdx.x & 63, w = threadIdx.x >> 6;
    const int row = blockIdx.x * 4 + w;
    const u16* xr = x + (size_t)row * 768;
    float v[12];
    float s = 0.f, s2 = 0.f;
#pragma unroll
    for (int i = 0; i < 3; ++i) {
        u16x4 u = *reinterpret_cast<const u16x4*>(xr + i * 256 + lane * 4);
#pragma unroll
        for (int jj = 0; jj < 4; ++jj) {
            float f = b2f(u[jj]);
            v[i * 4 + jj] = f;
            s += f;
            s2 += f * f;
        }
    }
#pragma unroll
    for (int off = 1; off < 64; off <<= 1) {
        s += __shfl_xor(s, off);
        s2 += __shfl_xor(s2, off);
    }
    const float mu = s * (1.0f / 768.0f);
    const float rstd = rsqrtf(s2 * (1.0f / 768.0f) - mu * mu + 1e-5f);
#pragma unroll
    for (int i = 0; i < 3; ++i) {
        int col = i * 256 + lane * 4;
        u16x4 o;
#pragma unroll
        for (int jj = 0; jj < 4; ++jj)
            o[jj] = f2b((v[i * 4 + jj] - mu) * rstd * g[col + jj] + bb[col + jj]);
        *reinterpret_cast<u16x4*>(out + (size_t)row * 768 + col) = o;
    }
}

// ------- all 4 weights fp32 [K][N] -> bf16 [N][K], one fused launch (32x32 tiles) -----
__global__ __launch_bounds__(256) void wconv4_k(const float* __restrict__ w0,
                                                const float* __restrict__ w1,
                                                const float* __restrict__ w2,
                                                const float* __restrict__ w3,
                                                u16* __restrict__ o0, u16* __restrict__ o1,
                                                u16* __restrict__ o2, u16* __restrict__ o3) {
    __shared__ float tile[32][33];
    const int id = blockIdx.x;
    const float* W;
    u16* WT;
    int K, N, loc;
    if (id < 1728) {            // w_attn 768x2304: 72x24 tiles
        W = w0; WT = o0; K = 768; N = 2304; loc = id;
    } else if (id < 2304) {     // w_proj 768x768: 24x24
        W = w1; WT = o1; K = 768; N = 768; loc = id - 1728;
    } else if (id < 4608) {     // w_fc1 768x3072: 96x24
        W = w2; WT = o2; K = 768; N = 3072; loc = id - 2304;
    } else {                    // w_fc2 3072x768: 24x96
        W = w3; WT = o3; K = 3072; N = 768; loc = id - 4608;
    }
    const int nx = N >> 5;
    const int n0 = (loc % nx) * 32, k0 = (loc / nx) * 32;
    const int tx = threadIdx.x, ty = threadIdx.y;
#pragma unroll
    for (int i = 0; i < 4; ++i)
        tile[ty + i * 8][tx] = W[(size_t)(k0 + ty + i * 8) * N + n0 + tx];
    __syncthreads();
#pragma unroll
    for (int i = 0; i < 4; ++i)
        WT[(size_t)(n0 + ty + i * 8) * K + k0 + tx] = f2b(tile[tx][ty + i * 8]);
}

// ------------- v (from qkv [8192][2304]) -> vT [96*64][1024] bf16 -------------
__global__ __launch_bounds__(256) void vtrans_k(const u16* __restrict__ qkv,
                                                u16* __restrict__ vT) {
    __shared__ u16 tile[32][33];
    const int tx = threadIdx.x, ty = threadIdx.y;
    const int t0 = blockIdx.x * 32, d0 = blockIdx.y * 32, bh = blockIdx.z;
    const int b = bh / 12, hd = bh % 12;
#pragma unroll
    for (int i = 0; i < 4; ++i)
        tile[ty + i * 8][tx] =
            qkv[(size_t)(b * 1024 + t0 + ty + i * 8) * 2304 + 1536 + hd * 64 + d0 + tx];
    __syncthreads();
#pragma unroll
    for (int i = 0; i < 4; ++i)
        vT[(size_t)(bh * 64 + d0 + ty + i * 8) * 1024 + t0 + tx] = tile[tx][ty + i * 8];
}

// ------------- GEMM 128x128, BK=32, 4 waves, 3-slot rotation (2-deep prefetch) ------
// MFAST=1: within each XCD chunk iterate M fastest (n outer) -> one W n-panel (<=200KB)
// + the XCD's A-slice (~1.6MB) stay L2-resident; W read once per XCD. Use when W > A-slice
// thrash risk (qkv/proj/fc1). MFAST=0: n fastest (r11 decode) — for fc2 (A-slice > L2).
// Both-sides XOR swizzle. RESIDT: 0 none, 1 fp32, 2 bf16.
template <int ACT, int RESIDT, int OUTBF, int MFAST>
__global__ __launch_bounds__(256) void gemm_bt(const u16* __restrict__ A,
                                               const u16* __restrict__ BT,
                                               const float* __restrict__ bias,
                                               const void* __restrict__ resid,
                                               void* __restrict__ out,
                                               int M, int N, int K) {
    __shared__ u16 As[3][128 * 32];
    __shared__ u16 Bs[3][128 * 32];
    const int tid = threadIdx.x, lane = tid & 63;
    const int l15 = lane & 15, lg = lane >> 4;
    const int nx = gridDim.x;
    const int bid = blockIdx.y * nx + blockIdx.x;
    const int xcd = bid & 7;
    const int c = bid >> 3;
    int mBase, nBase;
    if (MFAST) {
        const int mh = gridDim.y >> 3;          // m-panels per XCD
        mBase = (xcd * mh + (c % mh)) * 128;    // m fastest within chunk
        nBase = (c / mh) * 128;
    } else {
        const int q = (nx * gridDim.y) >> 3;
        const int swz = xcd * q + c;
        mBase = (swz / nx) * 128;
        nBase = (swz % nx) * 128;
    }
    const int w = tid >> 6, wr = w >> 1, wc = w & 1;

    auto stage = [&](int buf, int kk) {
        const int k0 = kk << 5;
#pragma unroll
        for (int i = 0; i < 2; ++i) {
            int cc = i * 256 + tid;
            int row = cc >> 2;
            int g = ((cc & 3) ^ ((row >> 1) & 3)) << 3;  // inverse swizzle on source
            async16(As[buf] + cc * 8, A + (size_t)(mBase + row) * K + k0 + g);
        }
#pragma unroll
        for (int i = 0; i < 2; ++i) {
            int cc = i * 256 + tid;
            int row = cc >> 2;
            int g = ((cc & 3) ^ ((row >> 1) & 3)) << 3;
            async16(Bs[buf] + cc * 8, BT + (size_t)(nBase + row) * K + k0 + g);
        }
    };

    f32x4 acc[4][4] = {};
    const int nsteps = K >> 5;
    stage(0, 0);
    stage(1, 1);
    int cur = 0;
    for (int kk = 0; kk < nsteps; ++kk) {
        if (kk + 2 < nsteps) {
            int nb = cur + 2;
            if (nb >= 3) nb -= 3;
            stage(nb, kk + 2);
            asm volatile("s_waitcnt vmcnt(8)" ::: "memory");
        } else if (kk + 1 < nsteps) {
            asm volatile("s_waitcnt vmcnt(4)" ::: "memory");
        } else {
            asm volatile("s_waitcnt vmcnt(0)" ::: "memory");
        }
        __builtin_amdgcn_s_barrier();
        asm volatile("" ::: "memory");

        bf16x8 af[4], bfr[4];
#pragma unroll
        for (int mi = 0; mi < 4; ++mi) {
            int rA = wr * 64 + mi * 16 + l15;
            af[mi] = load8(As[cur] + rA * 32 + ((lg ^ ((rA >> 1) & 3)) << 3));
        }
#pragma unroll
        for (int ni = 0; ni < 4; ++ni) {
            int rB = wc * 64 + ni * 16 + l15;
            bfr[ni] = load8(Bs[cur] + rB * 32 + ((lg ^ ((rB >> 1) & 3)) << 3));
        }
        __builtin_amdgcn_s_setprio(1);
#pragma unroll
        for (int mi = 0; mi < 4; ++mi)
#pragma unroll
            for (int ni = 0; ni < 4; ++ni)
                acc[mi][ni] = __builtin_amdgcn_mfma_f32_16x16x32_bf16(
                    af[mi], bfr[ni], acc[mi][ni], 0, 0, 0);
        __builtin_amdgcn_s_setprio(0);

        asm volatile("" ::: "memory");
        __builtin_amdgcn_s_barrier();   // readers done before slot reuse
        asm volatile("" ::: "memory");
        cur = (cur == 2) ? 0 : cur + 1;
    }
#pragma unroll
    for (int mi = 0; mi < 4; ++mi) {
#pragma unroll
        for (int ni = 0; ni < 4; ++ni) {
            const int row0 = mBase + wr * 64 + mi * 16 + lg * 4;
            const int col = nBase + wc * 64 + ni * 16 + l15;
            const float bv = bias[col];
#pragma unroll
            for (int r = 0; r < 4; ++r) {
                float v = acc[mi][ni][r] + bv;
                if (ACT == 1) v = gelu_t(v);
                size_t off = (size_t)(row0 + r) * N + col;
                if (RESIDT == 1) v += ((const float*)resid)[off];
                if (RESIDT == 2) v += b2f(((const u16*)resid)[off]);
                if (OUTBF)
                    ((u16*)out)[off] = f2b(v);
                else
                    ((float*)out)[off] = v;
            }
        }
    }
}

// ------------- causal flash attention: swapped QK^T + in-register softmax -------------
__global__ __launch_bounds__(256, 3) void attn_k(const u16* __restrict__ qkv,
                                                 const u16* __restrict__ vT,
                                                 u16* __restrict__ y) {
    __shared__ u16 Ks[2][64 * 64];
    __shared__ u16 Vs[2][64 * 64];
    __shared__ u16 Ps[4][2][16 * 64];
    const int tid = threadIdx.x, lane = tid & 63, w = tid >> 6;
    const int bid = blockIdx.x;
    const uint32_t permPk = 2u | (7u << 3) | (1u << 6) | (4u << 9) | (6u << 12) |
                            (0u << 15) | (5u << 18) | (3u << 21);
    const int qt = (permPk >> (((bid + (bid >> 8)) & 7) * 3)) & 7;
    const int bh = ((bid >> 8) << 5) + ((bid & 255) >> 3);
    const int b = bh / 12, hd = bh % 12;
    const int l15 = lane & 15, lg = lane >> 4;
    const int r0 = qt * 128 + w * 32;

    const float qscale = 0.125f * 1.4426950408889634f;
    bf16x8 qf[2][2];
#pragma unroll
    for (int m = 0; m < 2; ++m) {
        const u16* qb = qkv + (size_t)(b * 1024 + r0 + m * 16 + l15) * 2304 + hd * 64;
#pragma unroll
        for (int ks = 0; ks < 2; ++ks) {
            u16x8 u = *reinterpret_cast<const u16x8*>(qb + ks * 32 + lg * 8);
            u16x8 o;
#pragma unroll
            for (int jj = 0; jj < 8; ++jj) o[jj] = f2b(b2f(u[jj]) * qscale);
            qf[m][ks] = __builtin_bit_cast(bf16x8, o);
        }
    }

    const u16* kbase = qkv + (size_t)(b * 1024) * 2304 + 768 + hd * 64;
    const u16* vbase = vT + (size_t)(bh * 64) * 1024;

    auto stage = [&](int buf, int j) {
#pragma unroll
        for (int i = 0; i < 2; ++i) {
            int c = i * 256 + tid;
            int row = c >> 3, sc = ((c & 7) ^ (row & 7)) << 3;
            async16(Ks[buf] + c * 8, kbase + (size_t)(j * 64 + row) * 2304 + sc);
        }
#pragma unroll
        for (int i = 0; i < 2; ++i) {
            int c = i * 256 + tid;
            int row = c >> 3, sc = ((c & 7) ^ (row & 7)) << 3;
            async16(Vs[buf] + c * 8, vbase + (size_t)row * 1024 + j * 64 + sc);
        }
    };

    f32x4 oacc[2][4] = {};
    float mrow[2] = {-1e30f, -1e30f};
    float lrow[2] = {0.f, 0.f};

    const int jd = (r0 + 31) >> 6;
    const int jmax = qt * 2 + 1;

    stage(0, 0);
    for (int j = 0; j <= jmax; ++j) {
        const int cur = j & 1;
        if (j < jmax) {
            stage(cur ^ 1, j + 1);
            asm volatile("s_waitcnt vmcnt(4)" ::: "memory");
        } else {
            asm volatile("s_waitcnt vmcnt(0)" ::: "memory");
        }
        __builtin_amdgcn_s_barrier();
        asm volatile("" ::: "memory");

        if (j <= jd) {
            const bool diag = (j == jd);
            const u16* Kc = Ks[cur];
            const u16* Vc = Vs[cur];
            f32x4 s[2][4] = {};
            __builtin_amdgcn_s_setprio(1);
#pragma unroll
            for (int ks = 0; ks < 2; ++ks) {
                bf16x8 kf[4];
#pragma unroll
                for (int ni = 0; ni < 4; ++ni) {
                    int key = ni * 16 + l15;
                    kf[ni] = load8(Kc + key * 64 + (((ks * 4 + lg) ^ (key & 7)) << 3));
                }
#pragma unroll
                for (int ni = 0; ni < 4; ++ni) {
                    s[0][ni] = __builtin_amdgcn_mfma_f32_16x16x32_bf16(
                        kf[ni], qf[0][ks], s[0][ni], 0, 0, 0);
                    s[1][ni] = __builtin_amdgcn_mfma_f32_16x16x32_bf16(
                        kf[ni], qf[1][ks], s[1][ni], 0, 0, 0);
                }
            }
            __builtin_amdgcn_s_setprio(0);

#pragma unroll
            for (int m = 0; m < 2; ++m) {
                if (diag) {
                    const int qrow = r0 + m * 16 + l15;
#pragma unroll
                    for (int ni = 0; ni < 4; ++ni) {
                        int key = j * 64 + ni * 16 + lg * 4;
#pragma unroll
                        for (int r = 0; r < 4; ++r)
                            if (key + r > qrow) s[m][ni][r] = -1e30f;
                    }
                }
                float pmax = -1e30f;
#pragma unroll
                for (int ni = 0; ni < 4; ++ni)
#pragma unroll
                    for (int r = 0; r < 4; ++r) pmax = fmaxf(pmax, s[m][ni][r]);
                pmax = fmaxf(pmax, __shfl_xor(pmax, 16));
                pmax = fmaxf(pmax, __shfl_xor(pmax, 32));

                if (!__all(pmax <= mrow[m] + 8.0f)) {
                    float mnew = fmaxf(mrow[m], pmax);
                    float scal = exp2f(mrow[m] - mnew);
                    mrow[m] = mnew;
                    lrow[m] *= scal;
#pragma unroll
                    for (int r = 0; r < 4; ++r) {
                        float sr = __shfl(scal, lg * 4 + r);
#pragma unroll
                        for (int ni = 0; ni < 4; ++ni) oacc[m][ni][r] *= sr;
                    }
                }
                float psum = 0.f;
#pragma unroll
                for (int ni = 0; ni < 4; ++ni) {
                    u16x4 pk;
#pragma unroll
                    for (int r = 0; r < 4; ++r) {
                        float pv = exp2f(s[m][ni][r] - mrow[m]);
                        psum += pv;
                        pk[r] = f2b(pv);
                    }
                    *reinterpret_cast<u16x4*>(
                        &Ps[w][m][l15 * 64 + ((ni * 16 + lg * 4) ^ ((l15 & 7) << 3))]) =
                        pk;
                }
                psum += __shfl_xor(psum, 16);
                psum += __shfl_xor(psum, 32);
                lrow[m] += psum;
            }

            __builtin_amdgcn_s_setprio(1);
#pragma unroll
            for (int ks = 0; ks < 2; ++ks) {
                bf16x8 pf0 = load8(
                    &Ps[w][0][l15 * 64 + ((ks * 32 + lg * 8) ^ ((l15 & 7) << 3))]);
                bf16x8 pf1 = load8(
                    &Ps[w][1][l15 * 64 + ((ks * 32 + lg * 8) ^ ((l15 & 7) << 3))]);
                bf16x8 vf[4];
#pragma unroll
                for (int ni = 0; ni < 4; ++ni) {
                    int d = ni * 16 + l15;
                    vf[ni] = load8(Vc + d * 64 + (((ks * 4 + lg) ^ (d & 7)) << 3));
                }
#pragma unroll
                for (int ni = 0; ni < 4; ++ni) {
                    oacc[0][ni] = __builtin_amdgcn_mfma_f32_16x16x32_bf16(
                        pf0, vf[ni], oacc[0][ni], 0, 0, 0);
                    oacc[1][ni] = __builtin_amdgcn_mfma_f32_16x16x32_bf16(
                        pf1, vf[ni], oacc[1][ni], 0, 0, 0);
                }
            }
            __builtin_amdgcn_s_setprio(0);
        }
        asm volatile("" ::: "memory");
        __builtin_amdgcn_s_barrier();
        asm volatile("" ::: "memory");
    }

#pragma unroll
    for (int m = 0; m < 2; ++m) {
#pragma unroll
        for (int r = 0; r < 4; ++r) {
            float rl = 1.0f / __shfl(lrow[m], lg * 4 + r);
            int row = r0 + m * 16 + lg * 4 + r;
#pragma unroll
            for (int ni = 0; ni < 4; ++ni) {
                int col = hd * 64 + ni * 16 + l15;
                y[(size_t)(b * 1024 + row) * 768 + col] = f2b(oacc[m][ni][r] * rl);
            }
        }
    }
}

extern "C" void kernel_launch(void* const* d_in, const int* in_sizes, int n_in,
                              void* d_out, int out_size, void* d_ws, size_t ws_size,
                              hipStream_t stream) {
    const float* x      = (const float*)d_in[0];
    const float* ln1_g  = (const float*)d_in[1];
    const float* ln1_b  = (const float*)d_in[2];
    const float* w_attn = (const float*)d_in[3];
    const float* b_attn = (const float*)d_in[4];
    const float* w_proj = (const float*)d_in[5];
    const float* b_proj = (const float*)d_in[6];
    const float* ln2_g  = (const float*)d_in[7];
    const float* ln2_b  = (const float*)d_in[8];
    const float* w_fc1  = (const float*)d_in[9];
    const float* b_fc1  = (const float*)d_in[10];
    const float* w_fc2  = (const float*)d_in[11];
    const float* b_fc2  = (const float*)d_in[12];
    float* out = (float*)d_out;

    char* p = (char*)d_ws;
    auto take = [&](size_t n) {
        char* r = p;
        p += (n + 255) & ~(size_t)255;
        return r;
    };
    u16* wT_attn = (u16*)take((size_t)2304 * 768 * 2);
    u16* wT_proj = (u16*)take((size_t)768 * 768 * 2);
    u16* wT_fc1  = (u16*)take((size_t)3072 * 768 * 2);
    u16* wT_fc2  = (u16*)take((size_t)768 * 3072 * 2);
    u16* h       = (u16*)take((size_t)8192 * 768 * 2);   // h1 / h2 (aliased)
    u16* bufA    = (u16*)take((size_t)50331648);         // qkv+vT, later g1
    u16* yb      = (u16*)take((size_t)8192 * 768 * 2);
    u16* x1b     = (u16*)take((size_t)8192 * 768 * 2);   // residual stream, bf16
    u16* qkv = bufA;
    u16* vT  = bufA + (size_t)8192 * 2304;
    u16* g1  = bufA;

    const dim3 tb(32, 8);
    // all four weight convert+transpose in one launch
    wconv4_k<<<6912, tb, 0, stream>>>(w_attn, w_proj, w_fc1, w_fc2,
                                      wT_attn, wT_proj, wT_fc1, wT_fc2);
    // ln1
    ln_k<<<2048, 256, 0, stream>>>(x, ln1_g, ln1_b, h);
    // qkv = h @ w_attn + b_attn  -> bf16   (MFAST: W L2-resident per XCD)
    gemm_bt<0, 0, 1, 1><<<dim3(18, 64), 256, 0, stream>>>(h, wT_attn, b_attn, nullptr,
                                                          qkv, 8192, 2304, 768);
    // v transpose
    vtrans_k<<<dim3(32, 2, 96), tb, 0, stream>>>(qkv, vT);
    // attention
    attn_k<<<768, 256, 0, stream>>>(qkv, vT, yb);
    // x1b = bf16(x + y @ w_proj + b_proj)   (MFAST)
    gemm_bt<0, 1, 1, 1><<<dim3(6, 64), 256, 0, stream>>>(yb, wT_proj, b_proj, x,
                                                         x1b, 8192, 768, 768);
    // ln2 (bf16 input)
    ln_b16<<<2048, 256, 0, stream>>>(x1b, ln2_g, ln2_b, h);
    // g1 = gelu(h @ w_fc1 + b_fc1) -> bf16  (MFAST)
    gemm_bt<1, 0, 1, 1><<<dim3(24, 64), 256, 0, stream>>>(h, wT_fc1, b_fc1, nullptr,
                                                          g1, 8192, 3072, 768);
    // out = x1b + g1 @ w_fc2 + b_fc2  (fp32 out, bf16 resid; n-fastest: A-slice > L2)
    gemm_bt<0, 2, 0, 0><<<dim3(6, 64), 256, 0, stream>>>(g1, wT_fc2, b_fc2, x1b,
                                                         out, 8192, 768, 3072);
}

// Round 14
// 244.976 us; speedup vs baseline: 1.0985x; 1.0012x over previous
//
#include <hip/hip_runtime.h>
#include <cstdint>
#include <cmath>

typedef unsigned short u16;
typedef __bf16 bf16_t;
typedef bf16_t bf16x8 __attribute__((ext_vector_type(8)));
typedef float f32x4 __attribute__((ext_vector_type(4)));
typedef u16 u16x8 __attribute__((ext_vector_type(8)));
typedef u16 u16x4 __attribute__((ext_vector_type(4)));

#define DEV __device__ __forceinline__

DEV u16 f2b(float f) {
    uint32_t u = __builtin_bit_cast(uint32_t, f);
    u += 0x7FFFu + ((u >> 16) & 1u);
    return (u16)(u >> 16);
}
DEV float b2f(u16 h) { return __builtin_bit_cast(float, (uint32_t)h << 16); }

DEV bf16x8 load8(const u16* p) {
    return __builtin_bit_cast(bf16x8, *reinterpret_cast<const u16x8*>(p));
}

DEV void async16(void* lds, const void* g) {
    __builtin_amdgcn_global_load_lds(
        reinterpret_cast<const __attribute__((address_space(1))) void*>(
            reinterpret_cast<uintptr_t>(g)),
        reinterpret_cast<__attribute__((address_space(3))) void*>(
            reinterpret_cast<uintptr_t>(lds)),
        16, 0, 0);
}

DEV float gelu_t(float x) {
    float z = 0.7978845608028654f * (x + 0.044715f * x * x * x);
    z = fminf(fmaxf(z, -15.0f), 15.0f);
    float e = __expf(2.0f * z);
    return 0.5f * x * (1.0f + (e - 1.0f) / (e + 1.0f));
}

// ---------------- LayerNorm fp32-in: 1 wave per row of 768 -> bf16 ----------------
__global__ __launch_bounds__(256) void ln_k(const float* __restrict__ x,
                                            const float* __restrict__ g,
                                            const float* __restrict__ bb,
                                            u16* __restrict__ out) {
    const int lane = threadIdx.x & 63, w = threadIdx.x >> 6;
    const int row = blockIdx.x * 4 + w;
    const float4* xr = reinterpret_cast<const float4*>(x + (size_t)row * 768);
    float4 v[3];
    float s = 0.f, s2 = 0.f;
#pragma unroll
    for (int i = 0; i < 3; ++i) {
        v[i] = xr[i * 64 + lane];
        s += v[i].x + v[i].y + v[i].z + v[i].w;
        s2 += v[i].x * v[i].x + v[i].y * v[i].y + v[i].z * v[i].z + v[i].w * v[i].w;
    }
#pragma unroll
    for (int off = 1; off < 64; off <<= 1) {
        s += __shfl_xor(s, off);
        s2 += __shfl_xor(s2, off);
    }
    const float mu = s * (1.0f / 768.0f);
    const float rstd = rsqrtf(s2 * (1.0f / 768.0f) - mu * mu + 1e-5f);
#pragma unroll
    for (int i = 0; i < 3; ++i) {
        int col = i * 256 + lane * 4;
        u16x4 o;
        o[0] = f2b((v[i].x - mu) * rstd * g[col + 0] + bb[col + 0]);
        o[1] = f2b((v[i].y - mu) * rstd * g[col + 1] + bb[col + 1]);
        o[2] = f2b((v[i].z - mu) * rstd * g[col + 2] + bb[col + 2]);
        o[3] = f2b((v[i].w - mu) * rstd * g[col + 3] + bb[col + 3]);
        *reinterpret_cast<u16x4*>(out + (size_t)row * 768 + col) = o;
    }
}

// ---------------- LayerNorm bf16-in: 1 wave per row of 768 -> bf16 ----------------
__global__ __launch_bounds__(256) void ln_b16(const u16* __restrict__ x,
                                              const float* __restrict__ g,
                                              const float* __restrict__ bb,
                                              u16* __restrict__ out) {
    const int lane = threadIdx.x & 63, w = threadIdx.x >> 6;
    const int row = blockIdx.x * 4 + w;
    const u16* xr = x + (size_t)row * 768;
    float v[12];
    float s = 0.f, s2 = 0.f;
#pragma unroll
    for (int i = 0; i < 3; ++i) {
        u16x4 u = *reinterpret_cast<const u16x4*>(xr + i * 256 + lane * 4);
#pragma unroll
        for (int jj = 0; jj < 4; ++jj) {
            float f = b2f(u[jj]);
            v[i * 4 + jj] = f;
            s += f;
            s2 += f * f;
        }
    }
#pragma unroll
    for (int off = 1; off < 64; off <<= 1) {
        s += __shfl_xor(s, off);
        s2 += __shfl_xor(s2, off);
    }
    const float mu = s * (1.0f / 768.0f);
    const float rstd = rsqrtf(s2 * (1.0f / 768.0f) - mu * mu + 1e-5f);
#pragma unroll
    for (int i = 0; i < 3; ++i) {
        int col = i * 256 + lane * 4;
        u16x4 o;
#pragma unroll
        for (int jj = 0; jj < 4; ++jj)
            o[jj] = f2b((v[i * 4 + jj] - mu) * rstd * g[col + jj] + bb[col + jj]);
        *reinterpret_cast<u16x4*>(out + (size_t)row * 768 + col) = o;
    }
}

// ------- all 4 weights fp32 [K][N] -> bf16 [N][K], one fused launch (32x32 tiles) -----
__global__ __launch_bounds__(256) void wconv4_k(const float* __restrict__ w0,
                                                const float* __restrict__ w1,
                                                const float* __restrict__ w2,
                                                const float* __restrict__ w3,
                                                u16* __restrict__ o0, u16* __restrict__ o1,
                                                u16* __restrict__ o2, u16* __restrict__ o3) {
    __shared__ float tile[32][33];
    const int id = blockIdx.x;
    const float* W;
    u16* WT;
    int K, N, loc;
    if (id < 1728) {            // w_attn 768x2304: 72x24 tiles
        W = w0; WT = o0; K = 768; N = 2304; loc = id;
    } else if (id < 2304) {     // w_proj 768x768: 24x24
        W = w1; WT = o1; K = 768; N = 768; loc = id - 1728;
    } else if (id < 4608) {     // w_fc1 768x3072: 96x24
        W = w2; WT = o2; K = 768; N = 3072; loc = id - 2304;
    } else {                    // w_fc2 3072x768: 24x96
        W = w3; WT = o3; K = 3072; N = 768; loc = id - 4608;
    }
    const int nx = N >> 5;
    const int n0 = (loc % nx) * 32, k0 = (loc / nx) * 32;
    const int tx = threadIdx.x, ty = threadIdx.y;
#pragma unroll
    for (int i = 0; i < 4; ++i)
        tile[ty + i * 8][tx] = W[(size_t)(k0 + ty + i * 8) * N + n0 + tx];
    __syncthreads();
#pragma unroll
    for (int i = 0; i < 4; ++i)
        WT[(size_t)(n0 + ty + i * 8) * K + k0 + tx] = f2b(tile[tx][ty + i * 8]);
}

// ------------- v (from qkv [8192][2304]) -> vT [96*64][1024] bf16 -------------
__global__ __launch_bounds__(256) void vtrans_k(const u16* __restrict__ qkv,
                                                u16* __restrict__ vT) {
    __shared__ u16 tile[32][33];
    const int tx = threadIdx.x, ty = threadIdx.y;
    const int t0 = blockIdx.x * 32, d0 = blockIdx.y * 32, bh = blockIdx.z;
    const int b = bh / 12, hd = bh % 12;
#pragma unroll
    for (int i = 0; i < 4; ++i)
        tile[ty + i * 8][tx] =
            qkv[(size_t)(b * 1024 + t0 + ty + i * 8) * 2304 + 1536 + hd * 64 + d0 + tx];
    __syncthreads();
#pragma unroll
    for (int i = 0; i < 4; ++i)
        vT[(size_t)(bh * 64 + d0 + ty + i * 8) * 1024 + t0 + tx] = tile[tx][ty + i * 8];
}

// ------------- GEMM 128x128, BK=32, 4 waves, 3-slot rotation, ONE barrier/K-step ----
// Stage moved AFTER the barrier: with 3 slots and a single barrier per iter, waves are
// <=1 iter apart, so a wave staging slot (k+2)%3 after its iter-k barrier cannot race
// readers of that slot (they finished at the barrier). Per-wave vmcnt(4) BEFORE the
// barrier guarantees slot k's data (from all waves) is resident when the barrier opens.
// MFAST=1: m-fastest XCD decode (W L2-resident). RESIDT: 0 none, 1 fp32, 2 bf16.
template <int ACT, int RESIDT, int OUTBF, int MFAST>
__global__ __launch_bounds__(256) void gemm_bt(const u16* __restrict__ A,
                                               const u16* __restrict__ BT,
                                               const float* __restrict__ bias,
                                               const void* __restrict__ resid,
                                               void* __restrict__ out,
                                               int M, int N, int K) {
    __shared__ u16 As[3][128 * 32];
    __shared__ u16 Bs[3][128 * 32];
    const int tid = threadIdx.x, lane = tid & 63;
    const int l15 = lane & 15, lg = lane >> 4;
    const int nx = gridDim.x;
    const int bid = blockIdx.y * nx + blockIdx.x;
    const int xcd = bid & 7;
    const int c = bid >> 3;
    int mBase, nBase;
    if (MFAST) {
        const int mh = gridDim.y >> 3;          // m-panels per XCD
        mBase = (xcd * mh + (c % mh)) * 128;    // m fastest within chunk
        nBase = (c / mh) * 128;
    } else {
        const int q = (nx * gridDim.y) >> 3;
        const int swz = xcd * q + c;
        mBase = (swz / nx) * 128;
        nBase = (swz % nx) * 128;
    }
    const int w = tid >> 6, wr = w >> 1, wc = w & 1;

    auto stage = [&](int buf, int kk) {
        const int k0 = kk << 5;
#pragma unroll
        for (int i = 0; i < 2; ++i) {
            int cc = i * 256 + tid;
            int row = cc >> 2;
            int g = ((cc & 3) ^ ((row >> 1) & 3)) << 3;  // inverse swizzle on source
            async16(As[buf] + cc * 8, A + (size_t)(mBase + row) * K + k0 + g);
        }
#pragma unroll
        for (int i = 0; i < 2; ++i) {
            int cc = i * 256 + tid;
            int row = cc >> 2;
            int g = ((cc & 3) ^ ((row >> 1) & 3)) << 3;
            async16(Bs[buf] + cc * 8, BT + (size_t)(nBase + row) * K + k0 + g);
        }
    };

    f32x4 acc[4][4] = {};
    const int nsteps = K >> 5;
    stage(0, 0);
    stage(1, 1);
    int cur = 0;
    for (int kk = 0; kk < nsteps; ++kk) {
        if (kk + 1 < nsteps) {
            asm volatile("s_waitcnt vmcnt(4)" ::: "memory");  // slot kk landed (all waves)
        } else {
            asm volatile("s_waitcnt vmcnt(0)" ::: "memory");
        }
        __builtin_amdgcn_s_barrier();            // the ONLY barrier this K-step
        asm volatile("" ::: "memory");
        if (kk + 2 < nsteps) {
            int nb = cur + 2;
            if (nb >= 3) nb -= 3;
            stage(nb, kk + 2);                   // safe: readers of nb finished at barrier
        }

        bf16x8 af[4], bfr[4];
#pragma unroll
        for (int mi = 0; mi < 4; ++mi) {
            int rA = wr * 64 + mi * 16 + l15;
            af[mi] = load8(As[cur] + rA * 32 + ((lg ^ ((rA >> 1) & 3)) << 3));
        }
#pragma unroll
        for (int ni = 0; ni < 4; ++ni) {
            int rB = wc * 64 + ni * 16 + l15;
            bfr[ni] = load8(Bs[cur] + rB * 32 + ((lg ^ ((rB >> 1) & 3)) << 3));
        }
        __builtin_amdgcn_s_setprio(1);
#pragma unroll
        for (int mi = 0; mi < 4; ++mi)
#pragma unroll
            for (int ni = 0; ni < 4; ++ni)
                acc[mi][ni] = __builtin_amdgcn_mfma_f32_16x16x32_bf16(
                    af[mi], bfr[ni], acc[mi][ni], 0, 0, 0);
        __builtin_amdgcn_s_setprio(0);
        asm volatile("" ::: "memory");
        cur = (cur == 2) ? 0 : cur + 1;
    }
#pragma unroll
    for (int mi = 0; mi < 4; ++mi) {
#pragma unroll
        for (int ni = 0; ni < 4; ++ni) {
            const int row0 = mBase + wr * 64 + mi * 16 + lg * 4;
            const int col = nBase + wc * 64 + ni * 16 + l15;
            const float bv = bias[col];
#pragma unroll
            for (int r = 0; r < 4; ++r) {
                float v = acc[mi][ni][r] + bv;
                if (ACT == 1) v = gelu_t(v);
                size_t off = (size_t)(row0 + r) * N + col;
                if (RESIDT == 1) v += ((const float*)resid)[off];
                if (RESIDT == 2) v += b2f(((const u16*)resid)[off]);
                if (OUTBF)
                    ((u16*)out)[off] = f2b(v);
                else
                    ((float*)out)[off] = v;
            }
        }
    }
}

// ------------- causal flash attention: swapped QK^T + in-register softmax -------------
__global__ __launch_bounds__(256, 3) void attn_k(const u16* __restrict__ qkv,
                                                 const u16* __restrict__ vT,
                                                 u16* __restrict__ y) {
    __shared__ u16 Ks[2][64 * 64];
    __shared__ u16 Vs[2][64 * 64];
    __shared__ u16 Ps[4][2][16 * 64];
    const int tid = threadIdx.x, lane = tid & 63, w = tid >> 6;
    const int bid = blockIdx.x;
    const uint32_t permPk = 2u | (7u << 3) | (1u << 6) | (4u << 9) | (6u << 12) |
                            (0u << 15) | (5u << 18) | (3u << 21);
    const int qt = (permPk >> (((bid + (bid >> 8)) & 7) * 3)) & 7;
    const int bh = ((bid >> 8) << 5) + ((bid & 255) >> 3);
    const int b = bh / 12, hd = bh % 12;
    const int l15 = lane & 15, lg = lane >> 4;
    const int r0 = qt * 128 + w * 32;

    const float qscale = 0.125f * 1.4426950408889634f;
    bf16x8 qf[2][2];
#pragma unroll
    for (int m = 0; m < 2; ++m) {
        const u16* qb = qkv + (size_t)(b * 1024 + r0 + m * 16 + l15) * 2304 + hd * 64;
#pragma unroll
        for (int ks = 0; ks < 2; ++ks) {
            u16x8 u = *reinterpret_cast<const u16x8*>(qb + ks * 32 + lg * 8);
            u16x8 o;
#pragma unroll
            for (int jj = 0; jj < 8; ++jj) o[jj] = f2b(b2f(u[jj]) * qscale);
            qf[m][ks] = __builtin_bit_cast(bf16x8, o);
        }
    }

    const u16* kbase = qkv + (size_t)(b * 1024) * 2304 + 768 + hd * 64;
    const u16* vbase = vT + (size_t)(bh * 64) * 1024;

    auto stage = [&](int buf, int j) {
#pragma unroll
        for (int i = 0; i < 2; ++i) {
            int c = i * 256 + tid;
            int row = c >> 3, sc = ((c & 7) ^ (row & 7)) << 3;
            async16(Ks[buf] + c * 8, kbase + (size_t)(j * 64 + row) * 2304 + sc);
        }
#pragma unroll
        for (int i = 0; i < 2; ++i) {
            int c = i * 256 + tid;
            int row = c >> 3, sc = ((c & 7) ^ (row & 7)) << 3;
            async16(Vs[buf] + c * 8, vbase + (size_t)row * 1024 + j * 64 + sc);
        }
    };

    f32x4 oacc[2][4] = {};
    float mrow[2] = {-1e30f, -1e30f};
    float lrow[2] = {0.f, 0.f};

    const int jd = (r0 + 31) >> 6;
    const int jmax = qt * 2 + 1;

    stage(0, 0);
    for (int j = 0; j <= jmax; ++j) {
        const int cur = j & 1;
        if (j < jmax) {
            stage(cur ^ 1, j + 1);
            asm volatile("s_waitcnt vmcnt(4)" ::: "memory");
        } else {
            asm volatile("s_waitcnt vmcnt(0)" ::: "memory");
        }
        __builtin_amdgcn_s_barrier();
        asm volatile("" ::: "memory");

        if (j <= jd) {
            const bool diag = (j == jd);
            const u16* Kc = Ks[cur];
            const u16* Vc = Vs[cur];
            f32x4 s[2][4] = {};
            __builtin_amdgcn_s_setprio(1);
#pragma unroll
            for (int ks = 0; ks < 2; ++ks) {
                bf16x8 kf[4];
#pragma unroll
                for (int ni = 0; ni < 4; ++ni) {
                    int key = ni * 16 + l15;
                    kf[ni] = load8(Kc + key * 64 + (((ks * 4 + lg) ^ (key & 7)) << 3));
                }
#pragma unroll
                for (int ni = 0; ni < 4; ++ni) {
                    s[0][ni] = __builtin_amdgcn_mfma_f32_16x16x32_bf16(
                        kf[ni], qf[0][ks], s[0][ni], 0, 0, 0);
                    s[1][ni] = __builtin_amdgcn_mfma_f32_16x16x32_bf16(
                        kf[ni], qf[1][ks], s[1][ni], 0, 0, 0);
                }
            }
            __builtin_amdgcn_s_setprio(0);

#pragma unroll
            for (int m = 0; m < 2; ++m) {
                if (diag) {
                    const int qrow = r0 + m * 16 + l15;
#pragma unroll
                    for (int ni = 0; ni < 4; ++ni) {
                        int key = j * 64 + ni * 16 + lg * 4;
#pragma unroll
                        for (int r = 0; r < 4; ++r)
                            if (key + r > qrow) s[m][ni][r] = -1e30f;
                    }
                }
                float pmax = -1e30f;
#pragma unroll
                for (int ni = 0; ni < 4; ++ni)
#pragma unroll
                    for (int r = 0; r < 4; ++r) pmax = fmaxf(pmax, s[m][ni][r]);
                pmax = fmaxf(pmax, __shfl_xor(pmax, 16));
                pmax = fmaxf(pmax, __shfl_xor(pmax, 32));

                if (!__all(pmax <= mrow[m] + 8.0f)) {
                    float mnew = fmaxf(mrow[m], pmax);
                    float scal = exp2f(mrow[m] - mnew);
                    mrow[m] = mnew;
                    lrow[m] *= scal;
#pragma unroll
                    for (int r = 0; r < 4; ++r) {
                        float sr = __shfl(scal, lg * 4 + r);
#pragma unroll
                        for (int ni = 0; ni < 4; ++ni) oacc[m][ni][r] *= sr;
                    }
                }
                float psum = 0.f;
#pragma unroll
                for (int ni = 0; ni < 4; ++ni) {
                    u16x4 pk;
#pragma unroll
                    for (int r = 0; r < 4; ++r) {
                        float pv = exp2f(s[m][ni][r] - mrow[m]);
                        psum += pv;
                        pk[r] = f2b(pv);
                    }
                    *reinterpret_cast<u16x4*>(
                        &Ps[w][m][l15 * 64 + ((ni * 16 + lg * 4) ^ ((l15 & 7) << 3))]) =
                        pk;
                }
                psum += __shfl_xor(psum, 16);
                psum += __shfl_xor(psum, 32);
                lrow[m] += psum;
            }

            __builtin_amdgcn_s_setprio(1);
#pragma unroll
            for (int ks = 0; ks < 2; ++ks) {
                bf16x8 pf0 = load8(
                    &Ps[w][0][l15 * 64 + ((ks * 32 + lg * 8) ^ ((l15 & 7) << 3))]);
                bf16x8 pf1 = load8(
                    &Ps[w][1][l15 * 64 + ((ks * 32 + lg * 8) ^ ((l15 & 7) << 3))]);
                bf16x8 vf[4];
#pragma unroll
                for (int ni = 0; ni < 4; ++ni) {
                    int d = ni * 16 + l15;
                    vf[ni] = load8(Vc + d * 64 + (((ks * 4 + lg) ^ (d & 7)) << 3));
                }
#pragma unroll
                for (int ni = 0; ni < 4; ++ni) {
                    oacc[0][ni] = __builtin_amdgcn_mfma_f32_16x16x32_bf16(
                        pf0, vf[ni], oacc[0][ni], 0, 0, 0);
                    oacc[1][ni] = __builtin_amdgcn_mfma_f32_16x16x32_bf16(
                        pf1, vf[ni], oacc[1][ni], 0, 0, 0);
                }
            }
            __builtin_amdgcn_s_setprio(0);
        }
        asm volatile("" ::: "memory");
        __builtin_amdgcn_s_barrier();
        asm volatile("" ::: "memory");
    }

#pragma unroll
    for (int m = 0; m < 2; ++m) {
#pragma unroll
        for (int r = 0; r < 4; ++r) {
            float rl = 1.0f / __shfl(lrow[m], lg * 4 + r);
            int row = r0 + m * 16 + lg * 4 + r;
#pragma unroll
            for (int ni = 0; ni < 4; ++ni) {
                int col = hd * 64 + ni * 16 + l15;
                y[(size_t)(b * 1024 + row) * 768 + col] = f2b(oacc[m][ni][r] * rl);
            }
        }
    }
}

extern "C" void kernel_launch(void* const* d_in, const int* in_sizes, int n_in,
                              void* d_out, int out_size, void* d_ws, size_t ws_size,
                              hipStream_t stream) {
    const float* x      = (const float*)d_in[0];
    const float* ln1_g  = (const float*)d_in[1];
    const float* ln1_b  = (const float*)d_in[2];
    const float* w_attn = (const float*)d_in[3];
    const float* b_attn = (const float*)d_in[4];
    const float* w_proj = (const float*)d_in[5];
    const float* b_proj = (const float*)d_in[6];
    const float* ln2_g  = (const float*)d_in[7];
    const float* ln2_b  = (const float*)d_in[8];
    const float* w_fc1  = (const float*)d_in[9];
    const float* b_fc1  = (const float*)d_in[10];
    const float* w_fc2  = (const float*)d_in[11];
    const float* b_fc2  = (const float*)d_in[12];
    float* out = (float*)d_out;

    char* p = (char*)d_ws;
    auto take = [&](size_t n) {
        char* r = p;
        p += (n + 255) & ~(size_t)255;
        return r;
    };
    u16* wT_attn = (u16*)take((size_t)2304 * 768 * 2);
    u16* wT_proj = (u16*)take((size_t)768 * 768 * 2);
    u16* wT_fc1  = (u16*)take((size_t)3072 * 768 * 2);
    u16* wT_fc2  = (u16*)take((size_t)768 * 3072 * 2);
    u16* h       = (u16*)take((size_t)8192 * 768 * 2);   // h1 / h2 (aliased)
    u16* bufA    = (u16*)take((size_t)50331648);         // qkv+vT, later g1
    u16* yb      = (u16*)take((size_t)8192 * 768 * 2);
    u16* x1b     = (u16*)take((size_t)8192 * 768 * 2);   // residual stream, bf16
    u16* qkv = bufA;
    u16* vT  = bufA + (size_t)8192 * 2304;
    u16* g1  = bufA;

    const dim3 tb(32, 8);
    // all four weight convert+transpose in one launch
    wconv4_k<<<6912, tb, 0, stream>>>(w_attn, w_proj, w_fc1, w_fc2,
                                      wT_attn, wT_proj, wT_fc1, wT_fc2);
    // ln1
    ln_k<<<2048, 256, 0, stream>>>(x, ln1_g, ln1_b, h);
    // qkv = h @ w_attn + b_attn  -> bf16   (MFAST)
    gemm_bt<0, 0, 1, 1><<<dim3(18, 64), 256, 0, stream>>>(h, wT_attn, b_attn, nullptr,
                                                          qkv, 8192, 2304, 768);
    // v transpose
    vtrans_k<<<dim3(32, 2, 96), tb, 0, stream>>>(qkv, vT);
    // attention
    attn_k<<<768, 256, 0, stream>>>(qkv, vT, yb);
    // x1b = bf16(x + y @ w_proj + b_proj)   (MFAST)
    gemm_bt<0, 1, 1, 1><<<dim3(6, 64), 256, 0, stream>>>(yb, wT_proj, b_proj, x,
                                                         x1b, 8192, 768, 768);
    // ln2 (bf16 input)
    ln_b16<<<2048, 256, 0, stream>>>(x1b, ln2_g, ln2_b, h);
    // g1 = gelu(h @ w_fc1 + b_fc1) -> bf16  (MFAST)
    gemm_bt<1, 0, 1, 1><<<dim3(24, 64), 256, 0, stream>>>(h, wT_fc1, b_fc1, nullptr,
                                                          g1, 8192, 3072, 768);
    // out = x1b + g1 @ w_fc2 + b_fc2  (fp32 out, bf16 resid; n-fastest)
    gemm_bt<0, 2, 0, 0><<<dim3(6, 64), 256, 0, stream>>>(g1, wT_fc2, b_fc2, x1b,
                                                         out, 8192, 768, 3072);
}